// Round 8
// baseline (59.149 us; speedup 1.0000x reference)
//
#include <hip/hip_runtime.h>
#include <hip/hip_bf16.h>

// GCN: out[i] = deg_i * sum_{j in N(i)} deg_j * (X@W)[j]
// K0 prep: W -> Wt_g bf16 in MFMA A-frag order (32 chunks x 1024B;
//          lane l's 16B frag at chunk*1024 + l*16).
// K1 gemm: R7 body (2x8 pipelined X loads, operand-swapped MFMA, fused deg_j,
//          bf16 Xp) + cheap staging: 8x global_load_lds per wave from Wt_g.
//          Frag-ordered linear LDS -> conflict-free ds_read_b128.
// K2 agg:  exact R2/R7 agg (measured ~25us, at random-gather ceiling).

constexpr int D_IN  = 256;
constexpr int D_OUT = 64;

typedef short  s8v  __attribute__((ext_vector_type(8)));
typedef __bf16 bf8v __attribute__((ext_vector_type(8)));
typedef float  f32x4 __attribute__((ext_vector_type(4)));
typedef unsigned short us8v __attribute__((ext_vector_type(8)));

union BF8 { bf8v b; s8v s; };

__global__ void prep_w_kernel(const float* __restrict__ W,
                              unsigned short* __restrict__ Wt_g)
{
    const int t     = blockIdx.x * 256 + threadIdx.x;   // 0..2047 frags
    const int lane  = t & 63;
    const int chunk = t >> 6;          // 0..31 = ks*4 + f
    const int ks    = chunk >> 2;
    const int f     = chunk & 3;
    const int col   = f * 16 + (lane & 15);
    const int k0    = (lane >> 4) * 8 + ks * 32;
    us8v v;
    #pragma unroll
    for (int i = 0; i < 8; ++i) {
        __bf16 b = (__bf16)W[(size_t)(k0 + i) * D_OUT + col];
        v[i] = *reinterpret_cast<unsigned short*>(&b);
    }
    *reinterpret_cast<us8v*>(Wt_g + (size_t)t * 8) = v;
}

__global__ __launch_bounds__(256) void gemm_bf16_kernel(
    const float* __restrict__ X, const unsigned short* __restrict__ Wt_g,
    const float* __restrict__ deg, unsigned short* __restrict__ Xp,
    int n, int ntiles)
{
    __shared__ unsigned short Wt[32 * 512];   // 32 KB, frag-ordered

    const int tid  = threadIdx.x;
    const int wid  = tid >> 6;
    const int lane = tid & 63;

    // Stage: wave w loads chunks 8w..8w+7, 16B/lane, linear LDS dest.
    #pragma unroll
    for (int c = 0; c < 8; ++c) {
        const int chunk = wid * 8 + c;
        const unsigned short* src = Wt_g + (size_t)chunk * 512 + lane * 8;
        __builtin_amdgcn_global_load_lds(
            (const __attribute__((address_space(1))) void*)src,
            (__attribute__((address_space(3))) void*)&Wt[chunk * 512],
            16, 0, 0);
    }
    __syncthreads();

    const int tile = blockIdx.x * 4 + wid;
    if (tile >= ntiles) return;

    const int lrow = lane & 15;
    const int kgrp = lane >> 4;
    const int grow = tile * 16 + lrow;
    const int xr   = grow < n ? grow : n - 1;
    const float* xrow = X + (size_t)xr * D_IN + kgrp * 8;

    // ---- R7 software pipeline: two 8-load halves ----
    float4 xa[8], xb[8];
    #pragma unroll
    for (int k = 0; k < 4; ++k) {
        xa[2 * k]     = *reinterpret_cast<const float4*>(xrow + k * 32);
        xa[2 * k + 1] = *reinterpret_cast<const float4*>(xrow + k * 32 + 4);
    }
    #pragma unroll
    for (int k = 0; k < 4; ++k) {
        xb[2 * k]     = *reinterpret_cast<const float4*>(xrow + (k + 4) * 32);
        xb[2 * k + 1] = *reinterpret_cast<const float4*>(xrow + (k + 4) * 32 + 4);
    }

    f32x4 acc[4] = {};

    #pragma unroll
    for (int ks = 0; ks < 4; ++ks) {         // consume A (B in flight)
        BF8 xf;
        const float4 x0 = xa[2 * ks];
        const float4 x1 = xa[2 * ks + 1];
        xf.b[0] = (__bf16)x0.x; xf.b[1] = (__bf16)x0.y;
        xf.b[2] = (__bf16)x0.z; xf.b[3] = (__bf16)x0.w;
        xf.b[4] = (__bf16)x1.x; xf.b[5] = (__bf16)x1.y;
        xf.b[6] = (__bf16)x1.z; xf.b[7] = (__bf16)x1.w;
        #pragma unroll
        for (int f = 0; f < 4; ++f) {
            const s8v wf = *reinterpret_cast<const s8v*>(
                &Wt[(ks * 4 + f) * 512 + lane * 8]);
            acc[f] = __builtin_amdgcn_mfma_f32_16x16x32_bf16(wf, xf.s, acc[f], 0, 0, 0);
        }
    }
    #pragma unroll
    for (int ks = 4; ks < 8; ++ks) {         // consume B
        BF8 xf;
        const float4 x0 = xb[2 * (ks - 4)];
        const float4 x1 = xb[2 * (ks - 4) + 1];
        xf.b[0] = (__bf16)x0.x; xf.b[1] = (__bf16)x0.y;
        xf.b[2] = (__bf16)x0.z; xf.b[3] = (__bf16)x0.w;
        xf.b[4] = (__bf16)x1.x; xf.b[5] = (__bf16)x1.y;
        xf.b[6] = (__bf16)x1.z; xf.b[7] = (__bf16)x1.w;
        #pragma unroll
        for (int f = 0; f < 4; ++f) {
            const s8v wf = *reinterpret_cast<const s8v*>(
                &Wt[(ks * 4 + f) * 512 + lane * 8]);
            acc[f] = __builtin_amdgcn_mfma_f32_16x16x32_bf16(wf, xf.s, acc[f], 0, 0, 0);
        }
    }

    if (grow < n) {
        const float d = deg[grow];
        #pragma unroll
        for (int f = 0; f < 4; ++f) {
            ushort4 v;
            __bf16 b0 = (__bf16)(acc[f][0] * d);
            __bf16 b1 = (__bf16)(acc[f][1] * d);
            __bf16 b2 = (__bf16)(acc[f][2] * d);
            __bf16 b3 = (__bf16)(acc[f][3] * d);
            v.x = *reinterpret_cast<unsigned short*>(&b0);
            v.y = *reinterpret_cast<unsigned short*>(&b1);
            v.z = *reinterpret_cast<unsigned short*>(&b2);
            v.w = *reinterpret_cast<unsigned short*>(&b3);
            *reinterpret_cast<ushort4*>(
                &Xp[(size_t)grow * D_OUT + f * 16 + kgrp * 4]) = v;
        }
    }
}

__global__ __launch_bounds__(256) void agg_kernel(
    const unsigned short* __restrict__ Xp, const int* __restrict__ rp,
    const int* __restrict__ ci, const float* __restrict__ deg,
    float* __restrict__ out, int n)
{
    const int node = blockIdx.x * 32 + (threadIdx.x >> 3);
    if (node >= n) return;
    const int c8 = (threadIdx.x & 7) * 8;

    const int e0 = rp[node];
    const int e1 = rp[node + 1];
    const int m  = e1 - e0;
    const float d = deg[node];

    float acc[8] = {};

    if (m == 16 && (e0 & 3) == 0) {
        int4 i4[4];
        #pragma unroll
        for (int b = 0; b < 4; ++b)
            i4[b] = *reinterpret_cast<const int4*>(&ci[e0 + b * 4]);
        const int idx[16] = { i4[0].x, i4[0].y, i4[0].z, i4[0].w,
                              i4[1].x, i4[1].y, i4[1].z, i4[1].w,
                              i4[2].x, i4[2].y, i4[2].z, i4[2].w,
                              i4[3].x, i4[3].y, i4[3].z, i4[3].w };
        us8v v[16];
        #pragma unroll
        for (int j = 0; j < 16; ++j)
            v[j] = *reinterpret_cast<const us8v*>(&Xp[(size_t)idx[j] * D_OUT + c8]);
        #pragma unroll
        for (int j = 0; j < 16; ++j) {
            #pragma unroll
            for (int k = 0; k < 8; ++k)
                acc[k] += __uint_as_float((unsigned)v[j][k] << 16);
        }
    } else {
        for (int e = e0; e < e1; ++e) {
            const us8v v = *reinterpret_cast<const us8v*>(&Xp[(size_t)ci[e] * D_OUT + c8]);
            #pragma unroll
            for (int k = 0; k < 8; ++k)
                acc[k] += __uint_as_float((unsigned)v[k] << 16);
        }
    }

    float* op = out + (size_t)node * D_OUT + c8;
    *reinterpret_cast<float4*>(op)     = make_float4(acc[0]*d, acc[1]*d, acc[2]*d, acc[3]*d);
    *reinterpret_cast<float4*>(op + 4) = make_float4(acc[4]*d, acc[5]*d, acc[6]*d, acc[7]*d);
}

extern "C" void kernel_launch(void* const* d_in, const int* in_sizes, int n_in,
                              void* d_out, int out_size, void* d_ws, size_t ws_size,
                              hipStream_t stream)
{
    const float* X   = (const float*)d_in[0];
    const float* W   = (const float*)d_in[1];
    const int*   rp  = (const int*)d_in[2];
    const int*   ci  = (const int*)d_in[3];
    const float* deg = (const float*)d_in[4];
    float* out = (float*)d_out;

    const int n = in_sizes[4];   // N_NODES

    unsigned short* Xp   = (unsigned short*)d_ws;                        // n*64 bf16 = 12.8 MB
    unsigned short* Wt_g = (unsigned short*)((char*)d_ws + (16u << 20)); // 32 KB at +16MB

    prep_w_kernel<<<8, 256, 0, stream>>>(W, Wt_g);

    const int ntiles = (n + 15) / 16;           // 6250
    const int gemm_blocks = (ntiles + 3) / 4;   // 1563
    gemm_bf16_kernel<<<gemm_blocks, 256, 0, stream>>>(X, Wt_g, deg, Xp, n, ntiles);

    const int agg_blocks = (n + 31) / 32;
    agg_kernel<<<agg_blocks, 256, 0, stream>>>(Xp, rp, ci, deg, out, n);
}

// Round 9
// 57.703 us; speedup vs baseline: 1.0251x; 1.0251x over previous
//
#include <hip/hip_runtime.h>
#include <hip/hip_bf16.h>

// GCN: out[i] = deg_i * sum_{j in N(i)} deg_j * (X@W)[j]
// K1 gemm: R7 pipelined body (2x8 X loads), W transposed->LDS once per block,
//          grid-stride 1024 blocks (4 waves/SIMD exactly), fused deg_j, bf16 Xp.
// K2 agg:  exact R2/R7 agg (measured ~25us, at random-gather ceiling).

constexpr int D_IN  = 256;
constexpr int D_OUT = 64;
constexpr int WT_LD = D_IN + 8;

typedef short  s8v  __attribute__((ext_vector_type(8)));
typedef __bf16 bf8v __attribute__((ext_vector_type(8)));
typedef float  f32x4 __attribute__((ext_vector_type(4)));
typedef unsigned short us8v __attribute__((ext_vector_type(8)));

union BF8 { bf8v b; s8v s; };

__global__ __launch_bounds__(256) void gemm_bf16_kernel(
    const float* __restrict__ X, const float* __restrict__ W,
    const float* __restrict__ deg, unsigned short* __restrict__ Xp,
    int n, int ntiles)
{
    __shared__ __bf16 Wt[D_OUT][WT_LD];

    const int tid = threadIdx.x;

    // One-time per block: stage W transposed as bf16 (amortized over ~6 tiles).
    #pragma unroll
    for (int i = 0; i < 16; ++i) {
        const int f4 = tid + i * 256;
        const int k  = f4 >> 4;
        const int c4 = (f4 & 15) * 4;
        const float4 w = *reinterpret_cast<const float4*>(&W[(size_t)k * D_OUT + c4]);
        Wt[c4 + 0][k] = (__bf16)w.x;
        Wt[c4 + 1][k] = (__bf16)w.y;
        Wt[c4 + 2][k] = (__bf16)w.z;
        Wt[c4 + 3][k] = (__bf16)w.w;
    }
    __syncthreads();

    const int wid  = tid >> 6;
    const int lane = tid & 63;
    const int lrow = lane & 15;
    const int kgrp = lane >> 4;

    const __bf16* wt0 = &Wt[lrow][kgrp * 8];
    const int wstride = gridDim.x << 2;   // total waves

    for (int tile = blockIdx.x * 4 + wid; tile < ntiles; tile += wstride) {
        const int grow = tile * 16 + lrow;
        const int xr   = grow < n ? grow : n - 1;
        const float* xrow = X + (size_t)xr * D_IN + kgrp * 8;

        // ---- R7 software pipeline: two 8-load halves ----
        float4 xa[8], xb[8];
        #pragma unroll
        for (int k = 0; k < 4; ++k) {
            xa[2 * k]     = *reinterpret_cast<const float4*>(xrow + k * 32);
            xa[2 * k + 1] = *reinterpret_cast<const float4*>(xrow + k * 32 + 4);
        }
        #pragma unroll
        for (int k = 0; k < 4; ++k) {
            xb[2 * k]     = *reinterpret_cast<const float4*>(xrow + (k + 4) * 32);
            xb[2 * k + 1] = *reinterpret_cast<const float4*>(xrow + (k + 4) * 32 + 4);
        }

        f32x4 acc[4] = {};

        #pragma unroll
        for (int ks = 0; ks < 4; ++ks) {         // consume A (B in flight)
            BF8 xf;
            const float4 x0 = xa[2 * ks];
            const float4 x1 = xa[2 * ks + 1];
            xf.b[0] = (__bf16)x0.x; xf.b[1] = (__bf16)x0.y;
            xf.b[2] = (__bf16)x0.z; xf.b[3] = (__bf16)x0.w;
            xf.b[4] = (__bf16)x1.x; xf.b[5] = (__bf16)x1.y;
            xf.b[6] = (__bf16)x1.z; xf.b[7] = (__bf16)x1.w;
            #pragma unroll
            for (int f = 0; f < 4; ++f) {
                const s8v wf = *reinterpret_cast<const s8v*>(
                    wt0 + (size_t)f * 16 * WT_LD + ks * 32);
                acc[f] = __builtin_amdgcn_mfma_f32_16x16x32_bf16(wf, xf.s, acc[f], 0, 0, 0);
            }
        }
        #pragma unroll
        for (int ks = 4; ks < 8; ++ks) {         // consume B
            BF8 xf;
            const float4 x0 = xb[2 * (ks - 4)];
            const float4 x1 = xb[2 * (ks - 4) + 1];
            xf.b[0] = (__bf16)x0.x; xf.b[1] = (__bf16)x0.y;
            xf.b[2] = (__bf16)x0.z; xf.b[3] = (__bf16)x0.w;
            xf.b[4] = (__bf16)x1.x; xf.b[5] = (__bf16)x1.y;
            xf.b[6] = (__bf16)x1.z; xf.b[7] = (__bf16)x1.w;
            #pragma unroll
            for (int f = 0; f < 4; ++f) {
                const s8v wf = *reinterpret_cast<const s8v*>(
                    wt0 + (size_t)f * 16 * WT_LD + ks * 32);
                acc[f] = __builtin_amdgcn_mfma_f32_16x16x32_bf16(wf, xf.s, acc[f], 0, 0, 0);
            }
        }

        if (grow < n) {
            const float d = deg[grow];
            #pragma unroll
            for (int f = 0; f < 4; ++f) {
                ushort4 v;
                __bf16 b0 = (__bf16)(acc[f][0] * d);
                __bf16 b1 = (__bf16)(acc[f][1] * d);
                __bf16 b2 = (__bf16)(acc[f][2] * d);
                __bf16 b3 = (__bf16)(acc[f][3] * d);
                v.x = *reinterpret_cast<unsigned short*>(&b0);
                v.y = *reinterpret_cast<unsigned short*>(&b1);
                v.z = *reinterpret_cast<unsigned short*>(&b2);
                v.w = *reinterpret_cast<unsigned short*>(&b3);
                *reinterpret_cast<ushort4*>(
                    &Xp[(size_t)grow * D_OUT + f * 16 + kgrp * 4]) = v;
            }
        }
    }
}

__global__ __launch_bounds__(256) void agg_kernel(
    const unsigned short* __restrict__ Xp, const int* __restrict__ rp,
    const int* __restrict__ ci, const float* __restrict__ deg,
    float* __restrict__ out, int n)
{
    const int node = blockIdx.x * 32 + (threadIdx.x >> 3);
    if (node >= n) return;
    const int c8 = (threadIdx.x & 7) * 8;

    const int e0 = rp[node];
    const int e1 = rp[node + 1];
    const int m  = e1 - e0;
    const float d = deg[node];

    float acc[8] = {};

    if (m == 16 && (e0 & 3) == 0) {
        int4 i4[4];
        #pragma unroll
        for (int b = 0; b < 4; ++b)
            i4[b] = *reinterpret_cast<const int4*>(&ci[e0 + b * 4]);
        const int idx[16] = { i4[0].x, i4[0].y, i4[0].z, i4[0].w,
                              i4[1].x, i4[1].y, i4[1].z, i4[1].w,
                              i4[2].x, i4[2].y, i4[2].z, i4[2].w,
                              i4[3].x, i4[3].y, i4[3].z, i4[3].w };
        us8v v[16];
        #pragma unroll
        for (int j = 0; j < 16; ++j)
            v[j] = *reinterpret_cast<const us8v*>(&Xp[(size_t)idx[j] * D_OUT + c8]);
        #pragma unroll
        for (int j = 0; j < 16; ++j) {
            #pragma unroll
            for (int k = 0; k < 8; ++k)
                acc[k] += __uint_as_float((unsigned)v[j][k] << 16);
        }
    } else {
        for (int e = e0; e < e1; ++e) {
            const us8v v = *reinterpret_cast<const us8v*>(&Xp[(size_t)ci[e] * D_OUT + c8]);
            #pragma unroll
            for (int k = 0; k < 8; ++k)
                acc[k] += __uint_as_float((unsigned)v[k] << 16);
        }
    }

    float* op = out + (size_t)node * D_OUT + c8;
    *reinterpret_cast<float4*>(op)     = make_float4(acc[0]*d, acc[1]*d, acc[2]*d, acc[3]*d);
    *reinterpret_cast<float4*>(op + 4) = make_float4(acc[4]*d, acc[5]*d, acc[6]*d, acc[7]*d);
}

extern "C" void kernel_launch(void* const* d_in, const int* in_sizes, int n_in,
                              void* d_out, int out_size, void* d_ws, size_t ws_size,
                              hipStream_t stream)
{
    const float* X   = (const float*)d_in[0];
    const float* W   = (const float*)d_in[1];
    const int*   rp  = (const int*)d_in[2];
    const int*   ci  = (const int*)d_in[3];
    const float* deg = (const float*)d_in[4];
    float* out = (float*)d_out;
    unsigned short* Xp = (unsigned short*)d_ws;

    const int n = in_sizes[4];

    const int ntiles = (n + 15) / 16;   // 6250
    // 1024 blocks x 4 waves = 4096 waves = exactly 4 waves/SIMD device-wide;
    // each wave handles ~1.5 tiles, block preamble amortized.
    gemm_bf16_kernel<<<1024, 256, 0, stream>>>(X, W, deg, Xp, n, ntiles);

    const int agg_blocks = (n + 31) / 32;
    agg_kernel<<<agg_blocks, 256, 0, stream>>>(Xp, rp, ci, deg, out, n);
}